// Round 13
// baseline (168.935 us; speedup 1.0000x reference)
//
#include <hip/hip_runtime.h>
#include <hip/hip_bf16.h>
#include <hip/hip_cooperative_groups.h>

namespace cg = cooperative_groups;

// ---------------------------------------------------------------------------
// Math: C[z,c] = sum_m coef[z,m] * T[iv_z][m][c], K=18.
//   T[iv][y][c] = sum_w A[iv,w]*Q[c,y,w]; T[iv][9+y][c] = sum_w B[iv,w]*Q[c,y,w]
//   coef[m<9] = Ysh*t, coef[9+y] = Ysh.  Counting sort by iv, no global atomics.
// Round-13: cooperative single-kernel path with grid computed from the
// occupancy API and RETURN CODES CHECKED (round 12 launched 1024 blocks
// blind; runtime max was likely 512 -> silent no-op). Fallback = proven
// round-11 3-kernel pipeline sharing the same __device__ phase bodies.
// ws layout = round 11 (peak 2,692,368 B, proven safe).
// ---------------------------------------------------------------------------

typedef __attribute__((ext_vector_type(8))) short bfrag;   // 8 x bf16
typedef __attribute__((ext_vector_type(4))) float fx4;     // 16x16 accum

#define WS_AT   512
#define WS_BT   50048
#define WS_QT   99584       // bf16[129][16384B] = 2113536
#define WS_IVZ  2213120     // u16[65536]
#define WS_PERM 2344192     // u32[65536]
#define WS_BH   2606336     // u16[256][132]
#define WS_BTAB 2673920     // uint4[1153]  (peak 2692368)
#define NCHUNKS 1153
#define NQTBLK  1161
#define NUNITS_A 385
#define NUNITS_B (NQTBLK + 256)   // 1417
#define SMEM_BYTES 25856

__device__ inline unsigned short f2bf(float f) {   // RNE float->bf16
  union { float f; unsigned int u; } v; v.f = f;
  unsigned int r = v.u + 0x7FFFu + ((v.u >> 16) & 1u);
  return (unsigned short)(r >> 16);
}
__device__ inline unsigned int pack2(float a, float b) {
  return (unsigned int)f2bf(a) | ((unsigned int)f2bf(b) << 16);
}
__device__ inline void gl_lds16(const void* g, void* l) {
  __builtin_amdgcn_global_load_lds(
      (const __attribute__((address_space(1))) unsigned int*)g,
      (__attribute__((address_space(3))) unsigned int*)l, 16, 0, 0);
}

// ======================= phase bodies (shared) =======================

__device__ __forceinline__
void phaseA_unit(int u, int tid, char* smem,
                 const float* __restrict__ W1, const float* __restrict__ b1,
                 const float* __restrict__ W2, const float* __restrict__ b2,
                 const float* __restrict__ r,
                 float* __restrict__ At, float* __restrict__ Bt,
                 unsigned short* __restrict__ ivz, unsigned short* __restrict__ bh) {
  const float INF = __builtin_inff();
  if (u < 256) {
    // ---- iv unit: points [u*256, u*256+256) ----
    float* tj_s = (float*)smem;                        // 512 B
    unsigned int* h_s = (unsigned int*)(smem + 512);   // 516 B
    if (tid < 128) {
      float w1 = W1[tid], b1v = b1[tid];
      float tj = -b1v / w1;
      bool valid = (w1 != 0.0f) && (tj > 0.0f);
      tj_s[tid] = valid ? tj : INF;
    }
    if (tid < 129) h_s[tid] = 0;
    __syncthreads();
    const int z = u * 256 + tid;
    float rx = r[z * 3 + 0], ry = r[z * 3 + 1], rz = r[z * 3 + 2];
    float rad = sqrtf(rx * rx + ry * ry + rz * rz);
    int cnt = 0;
#pragma unroll 16
    for (int j = 0; j < 128; ++j) cnt += (tj_s[j] < rad) ? 1 : 0;
    ivz[z] = (unsigned short)(cnt | (rad > 0.f ? 0 : 0x8000));
    atomicAdd(&h_s[cnt], 1u);
    __syncthreads();
    if (tid < 129) bh[u * 132 + tid] = (unsigned short)h_s[tid];
  } else {
    // ---- table unit for interval tiv ----
    const int tiv = u - 256;                           // 0..128
    float* w1_s  = (float*)smem;
    float* b1_s  = w1_s + 128;
    float* val_s = b1_s + 128;
    float* stb_s = val_s + 128;                        // total 2048 B
    if (tid < 128) {
      float w1 = W1[tid], b1v = b1[tid];
      w1_s[tid] = w1; b1_s[tid] = b1v;
      float tj = -b1v / w1;
      bool valid = (w1 != 0.0f) && (tj > 0.0f);
      val_s[tid] = valid ? tj : INF;
    }
    __syncthreads();
    if (tid < 128) {                                   // stable rank sort
      float v = val_s[tid];
      int rank = 0;
      for (int m = 0; m < 128; ++m) {
        float vm = val_s[m];
        rank += (vm < v || (vm == v && m < tid)) ? 1 : 0;
      }
      stb_s[rank] = v;
    }
    __syncthreads();
    if (tid < 96) {
      float lo_e = (tiv == 0) ? 0.f : stb_s[tiv - 1];
      float hi_e = (tiv < 128) ? stb_s[tiv] : INF;
      float tstar;
      if (lo_e < INF) tstar = (hi_e < INF) ? 0.5f * (lo_e + hi_e) : (lo_e + 1.0f);
      else            tstar = 0.f;                     // empty bucket; unused
      float sa = 0.f, sb = 0.f;
#pragma unroll 8
      for (int j = 0; j < 128; ++j) {
        float on = (w1_s[j] * tstar + b1_s[j] > 0.0f) ? 1.f : 0.f;
        float w2 = on * W2[j * 96 + tid];              // coalesced across tid
        sa += w2 * w1_s[j]; sb += w2 * b1_s[j];
      }
      At[tiv * 96 + tid] = sa;
      Bt[tiv * 96 + tid] = sb + b2[tid];
    }
  }
}

__device__ __forceinline__
void phaseB_unit(int u, int tid, char* smem,
                 const float* __restrict__ Q, const float* __restrict__ At,
                 const float* __restrict__ Bt,
                 const unsigned short* __restrict__ ivz,
                 const unsigned short* __restrict__ bh,
                 unsigned short* __restrict__ qt,
                 unsigned int* __restrict__ perm, uint4* __restrict__ btab) {
  if (u < NQTBLK) {
    // ---- qt unit (iv, y): quarter-pass staged dot ----
    float* at_s = (float*)smem;               // 96
    float* bt_s = at_s + 96;                  // 96
    float* qs   = bt_s + 96;                  // [128][49] = 25088 B (tot 25856)
    const int iv = u % 129, y = u / 129;
    if (tid < 96) { at_s[tid] = At[iv * 96 + tid]; bt_s[tid] = Bt[iv * 96 + tid]; }
#pragma unroll
    for (int half = 0; half < 2; ++half) {
      float qa = 0.f, qb = 0.f;
#pragma unroll
      for (int wh = 0; wh < 2; ++wh) {
        __syncthreads();
        for (int i = tid; i < 128 * 12; i += 256) {
          const int c_loc = i / 12, f4 = i - c_loc * 12;
          float4 v = *(const float4*)(Q + (size_t)(half * 128 + c_loc) * 864
                                      + y * 96 + wh * 48 + f4 * 4);
          float* d = qs + c_loc * 49 + f4 * 4;
          d[0] = v.x; d[1] = v.y; d[2] = v.z; d[3] = v.w;
        }
        __syncthreads();
        if (tid < 128) {
          const float* row = qs + tid * 49;
          const float* as = at_s + wh * 48;
          const float* bs = bt_s + wh * 48;
#pragma unroll 8
          for (int w = 0; w < 48; ++w) {
            float qv = row[w];
            qa += qv * as[w]; qb += qv * bs[w];
          }
        }
      }
      if (tid < 128) {
        const int c = half * 128 + tid;
        char* base = (char*)qt + (size_t)iv * 16384 + (c >> 4) * 1024 + (c & 15) * 16;
        const int kb = 9 + y;
        *(unsigned short*)(base + (y >> 3) * 256 + (y & 7) * 2) = f2bf(qa);
        *(unsigned short*)(base + (kb >> 3) * 256 + (kb & 7) * 2) = f2bf(qb);
        if (y == 0) {
#pragma unroll
          for (int k = 18; k < 32; ++k)
            *(unsigned short*)(base + (k >> 3) * 256 + (k & 7) * 2) = 0;
        }
      }
    }
  } else {
    // ---- scatter unit bb: points [bb*256, bb*256+256) ----
    unsigned int* tot_s = (unsigned int*)smem;  // 129
    unsigned int* pre_s = tot_s + 129;          // 129
    unsigned int* st_s  = pre_s + 129;          // 130
    unsigned int* eo_s  = st_s + 130;           // 130
    unsigned int* cur_s = eo_s + 130;           // 129  (2588 B)
    const int bb = u - NQTBLK;                  // 0..255
    if (tid < 129) {
      unsigned tot = 0, pre = 0;
#pragma unroll 8
      for (int b = 0; b < 256; ++b) {
        unsigned v = bh[b * 132 + tid];
        tot += v;
        pre += (b < bb) ? v : 0;
      }
      tot_s[tid] = tot; pre_s[tid] = pre;
    }
    __syncthreads();
    if (tid == 0) {
      unsigned s = 0, e = 0;
      for (int i = 0; i < 129; ++i) {
        st_s[i] = s; eo_s[i] = e;
        s += tot_s[i]; e += (tot_s[i] + 63) >> 6;
      }
      st_s[129] = s; eo_s[129] = e;
    }
    __syncthreads();
    if (tid < 129) cur_s[tid] = st_s[tid] + pre_s[tid];
    __syncthreads();
    const int z = bb * 256 + tid;
    unsigned uu = ivz[z];
    unsigned iv = uu & 255u;
    unsigned pos = atomicAdd(&cur_s[iv], 1u);
    perm[pos] = (unsigned)z | ((uu & 0x8000u) << 16);
    if (bb == 0) {
      const unsigned total = eo_s[129];
      for (unsigned e = tid; e < NCHUNKS; e += 256) {
        uint4 ent = make_uint4(0, 0, 0, 0);
        if (e < total) {
          int lo = 0, hi = 128;
          while (lo < hi) { int mid = (lo + hi + 1) >> 1;
                            if (eo_s[mid] <= e) lo = mid; else hi = mid - 1; }
          unsigned chunk = e - eo_s[lo];
          unsigned cnt2 = tot_s[lo] - chunk * 64; if (cnt2 > 64) cnt2 = 64;
          ent = make_uint4((unsigned)lo, st_s[lo] + chunk * 64, cnt2, 0);
        }
        btab[e] = ent;
      }
    }
  }
}

__device__ __forceinline__
void phaseC_unit(int u, int tid, char* smem,
                 const float* __restrict__ r, const unsigned short* __restrict__ qt,
                 const unsigned int* __restrict__ perm, const uint4* __restrict__ btab,
                 const float* __restrict__ K0, float* __restrict__ out) {
  unsigned short* T_s    = (unsigned short*)smem;            // 16384 B
  unsigned short* coef_s = (unsigned short*)(smem + 16384);  //  4096 B
  unsigned int*   z_s    = (unsigned int*)(smem + 20480);    //   256 B
  unsigned int*   mk_s   = (unsigned int*)(smem + 20736);    //   256 B
  const int lane = tid & 63;
  const int wave = tid >> 6;
  const int lg   = lane >> 4;
  const int l15  = lane & 15;

  const uint4 ent = btab[u];
  const unsigned iv = ent.x, base = ent.y, cnt = ent.z;
  if (cnt == 0) return;                       // block-uniform

  unsigned pz = 0;
  if (tid < 64) pz = perm[base + (tid < (int)cnt ? tid : 0)];

  // stage T[iv] (16 KB) via async global->LDS
  {
    const char* src = (const char*)qt + (size_t)iv * 16384 + wave * 1024 + lane * 16;
    char* dst = (char*)T_s + wave * 1024;
#pragma unroll
    for (int i = 0; i < 4; ++i) gl_lds16(src + i * 4096, dst + i * 4096);
  }

  if (tid < 64) {
    const int j = tid;
    unsigned z = pz & 0x7FFFFFFFu;
    z_s[j] = z; mk_s[j] = pz >> 31;
    const float* rg = r + (size_t)z * 3;
    float rx = rg[0], ry = rg[1], rz = rg[2];
    float rad = sqrtf(rx * rx + ry * ry + rz * rz);
    float inv = (rad > 0.f) ? (1.0f / rad) : 1.0f;
    float x = rx * inv, y = ry * inv, zc = rz * inv;
    const float SQ3 = 1.7320508075688772f, SQ5 = 2.2360679774997896f,
                SQ15 = 3.872983346207417f;
    float ys[9];
    ys[0] = 1.f;
    ys[1] = SQ3 * y;  ys[2] = SQ3 * zc;  ys[3] = SQ3 * x;
    ys[4] = SQ15 * x * y;  ys[5] = SQ15 * y * zc;
    ys[6] = 0.5f * SQ5 * (3.f * zc * zc - 1.f);
    ys[7] = SQ15 * x * zc;
    ys[8] = 0.5f * SQ15 * (x * x - y * y);
    float cf[18];
#pragma unroll
    for (int m = 0; m < 9; ++m) { cf[m] = ys[m] * rad; cf[9 + m] = ys[m]; }
    char* cbp = (char*)coef_s + (j >> 4) * 1024 + (j & 15) * 16;
#pragma unroll
    for (int g = 0; g < 4; ++g)
#pragma unroll
      for (int p = 0; p < 4; ++p) {
        const int k0 = g * 8 + p * 2, k1 = k0 + 1;
        float v0 = (k0 < 18) ? cf[k0] : 0.f;
        float v1 = (k1 < 18) ? cf[k1] : 0.f;
        *(unsigned int*)(cbp + g * 256 + p * 4) = pack2(v0, v1);
      }
  }
  __syncthreads();   // T_s (vmcnt) + coef_s published

  fx4 acc[16];
#pragma unroll
  for (int cb2 = 0; cb2 < 16; ++cb2)
#pragma unroll
    for (int e = 0; e < 4; ++e) acc[cb2][e] = 0.f;

  const bfrag a = *(const bfrag*)((char*)coef_s + wave * 1024 + lg * 256 + l15 * 16);
#pragma unroll
  for (int cb2 = 0; cb2 < 16; ++cb2) {
    const bfrag b = *(const bfrag*)((char*)T_s + cb2 * 1024 + lg * 256 + l15 * 16);
    acc[cb2] = __builtin_amdgcn_mfma_f32_16x16x32_bf16(a, b, acc[cb2], 0, 0, 0);
  }

  float k0v[16];
#pragma unroll
  for (int cb2 = 0; cb2 < 16; ++cb2) k0v[cb2] = K0[cb2 * 16 + l15];
#pragma unroll
  for (int q = 0; q < 4; ++q) {
    const int br = wave * 16 + lg * 4 + q;
    if (br < (int)cnt) {
      const unsigned z = z_s[br];
      const bool mq = mk_s[br] != 0;
      float* ob = out + (size_t)z * 256 + l15;
#pragma unroll
      for (int cb2 = 0; cb2 < 16; ++cb2)
        ob[cb2 * 16] = mq ? k0v[cb2] : acc[cb2][q];
    }
  }
}

// ======================= kernels =======================

__global__ __launch_bounds__(256, 4)
void k_fused(const float* __restrict__ r, const float* __restrict__ Q,
             const float* __restrict__ W1, const float* __restrict__ b1,
             const float* __restrict__ W2, const float* __restrict__ b2,
             const float* __restrict__ K0, float* __restrict__ out,
             float* __restrict__ At, float* __restrict__ Bt,
             unsigned short* __restrict__ qt, unsigned short* __restrict__ ivz,
             unsigned int* __restrict__ perm, unsigned short* __restrict__ bh,
             uint4* __restrict__ btab) {
  __shared__ __align__(16) char smem[SMEM_BYTES];
  const int tid = threadIdx.x;
  const int g = gridDim.x;
  cg::grid_group grid = cg::this_grid();

  for (int u = blockIdx.x; u < NUNITS_A; u += g) {
    __syncthreads();
    phaseA_unit(u, tid, smem, W1, b1, W2, b2, r, At, Bt, ivz, bh);
  }
  grid.sync();
  for (int u = blockIdx.x; u < NUNITS_B; u += g) {
    __syncthreads();
    phaseB_unit(u, tid, smem, Q, At, Bt, ivz, bh, qt, perm, btab);
  }
  grid.sync();
  for (int u = blockIdx.x; u < NCHUNKS; u += g) {
    __syncthreads();
    phaseC_unit(u, tid, smem, r, qt, perm, btab, K0, out);
  }
}

__global__ __launch_bounds__(256)
void k_pre(const float* __restrict__ W1, const float* __restrict__ b1,
           const float* __restrict__ W2, const float* __restrict__ b2,
           const float* __restrict__ r, float* __restrict__ At,
           float* __restrict__ Bt, unsigned short* __restrict__ ivz,
           unsigned short* __restrict__ bh) {
  __shared__ __align__(16) char smem[2064];
  phaseA_unit(blockIdx.x, threadIdx.x, smem, W1, b1, W2, b2, r, At, Bt, ivz, bh);
}

__global__ __launch_bounds__(256)
void k_mid(const float* __restrict__ Q, const float* __restrict__ At,
           const float* __restrict__ Bt, const unsigned short* __restrict__ ivz,
           const unsigned short* __restrict__ bh, unsigned short* __restrict__ qt,
           unsigned int* __restrict__ perm, uint4* __restrict__ btab) {
  __shared__ __align__(16) char smem[SMEM_BYTES];
  phaseB_unit(blockIdx.x, threadIdx.x, smem, Q, At, Bt, ivz, bh, qt, perm, btab);
}

__global__ __launch_bounds__(256)
void k_out(const float* __restrict__ r, const unsigned short* __restrict__ qt,
           const unsigned int* __restrict__ perm, const uint4* __restrict__ btab,
           const float* __restrict__ K0, float* __restrict__ out) {
  __shared__ __align__(16) char smem[20992];
  phaseC_unit(blockIdx.x, threadIdx.x, smem, r, qt, perm, btab, K0, out);
}

// ---------------------------------------------------------------------------
extern "C" void kernel_launch(void* const* d_in, const int* in_sizes, int n_in,
                              void* d_out, int out_size, void* d_ws, size_t ws_size,
                              hipStream_t stream) {
  const float* r  = (const float*)d_in[0];
  const float* Q  = (const float*)d_in[1];
  const float* W1 = (const float*)d_in[2];
  const float* b1 = (const float*)d_in[3];
  const float* W2 = (const float*)d_in[4];
  const float* b2 = (const float*)d_in[5];
  const float* K0 = (const float*)d_in[6];
  float* out = (float*)d_out;
  char* ws = (char*)d_ws;
  float* At = (float*)(ws + WS_AT);
  float* Bt = (float*)(ws + WS_BT);
  unsigned short* qt  = (unsigned short*)(ws + WS_QT);
  unsigned short* ivz = (unsigned short*)(ws + WS_IVZ);
  unsigned int* permb = (unsigned int*)(ws + WS_PERM);
  unsigned short* bh  = (unsigned short*)(ws + WS_BH);
  uint4* btab         = (uint4*)(ws + WS_BTAB);

  // ---- cooperative path: grid from occupancy API, return codes checked ----
  int coopAttr = 0, numCU = 0, nbPerCU = 0;
  bool coop_ok = false;
  if (hipDeviceGetAttribute(&coopAttr, hipDeviceAttributeCooperativeLaunch, 0)
          == hipSuccess && coopAttr) {
    if (hipDeviceGetAttribute(&numCU, hipDeviceAttributeMultiprocessorCount, 0)
            == hipSuccess && numCU > 0) {
      if (hipOccupancyMaxActiveBlocksPerMultiprocessor(&nbPerCU, k_fused, 256, 0)
              == hipSuccess && nbPerCU > 0) {
        coop_ok = true;
      }
    }
  }
  if (coop_ok) {
    int grid = nbPerCU * numCU;
    if (grid > 1024) grid = 1024;
    void* kargs[] = {
      (void*)&r, (void*)&Q, (void*)&W1, (void*)&b1, (void*)&W2, (void*)&b2,
      (void*)&K0, (void*)&out, (void*)&At, (void*)&Bt, (void*)&qt,
      (void*)&ivz, (void*)&permb, (void*)&bh, (void*)&btab
    };
    if (hipLaunchCooperativeKernel(reinterpret_cast<void*>(k_fused),
                                   dim3(grid), dim3(256), kargs, 0, stream)
            == hipSuccess) {
      return;
    }
  }

  // ---- fallback: proven 3-kernel pipeline (same phase bodies) ----
  hipLaunchKernelGGL(k_pre, dim3(NUNITS_A), dim3(256), 0, stream,
                     W1, b1, W2, b2, r, At, Bt, ivz, bh);
  hipLaunchKernelGGL(k_mid, dim3(NUNITS_B), dim3(256), 0, stream,
                     Q, At, Bt, ivz, bh, qt, permb, btab);
  hipLaunchKernelGGL(k_out, dim3(NCHUNKS), dim3(256), 0, stream,
                     r, qt, permb, btab, K0, out);
}